// Round 7
// baseline (90.256 us; speedup 1.0000x reference)
//
#include <hip/hip_runtime.h>
#include <hip/hip_bf16.h>

typedef __attribute__((ext_vector_type(4))) float f32x4;
typedef __attribute__((ext_vector_type(8))) short bf16x8;

struct Smem {
    float inp[384];        // base input vector (real actions), f32
    float part[4][64];     // per-wave layer-1 hidden partials
    float base[64];        // b1 + hidden-part of layer 1
    float subsum[64];      // sum_g W1[selected action row of g]
    float sub[8][64];      // W1 row of agent g's real action
    int   sel[8];          // real-action index per agent
};

template<bool ISF32>
__device__ __forceinline__ float ldin(const void* p, int i) {
    if constexpr (ISF32) return ((const float*)p)[i];
    else return __bfloat162float(((const __hip_bfloat16*)p)[i]);
}

template<bool ISF32>
__device__ __forceinline__ f32x4 ldq(const void* p, int i) {
    if constexpr (ISF32) return *(const f32x4*)((const float*)p + i);
    else {
        const __hip_bfloat16* q = (const __hip_bfloat16*)p + i;
        return (f32x4){__bfloat162float(q[0]), __bfloat162float(q[1]),
                       __bfloat162float(q[2]), __bfloat162float(q[3])};
    }
}

__device__ __forceinline__ short bf16bits(float v) {
    __hip_bfloat16 h = __float2bfloat16(v);
    return *(const short*)&h;
}
__device__ __forceinline__ float bf16val(short s) {
    return __bfloat162float(*(const __hip_bfloat16*)&s);
}

__device__ __forceinline__ bool word_looks_bf16(unsigned int w) {
    const unsigned int lo = w & 0xFFFFu;
    const unsigned int ex = (lo >> 7) & 0xFFu;
    return (ex >= 100u && ex <= 140u) || (lo & 0x7FFFu) == 0u;
}

__device__ __forceinline__ bool vote_isf32_scalar(const void* hidden) {
    const unsigned int* hw = (const unsigned int*)hidden;
    int cnt = 0;
    #pragma unroll
    for (int i = 0; i < 32; ++i) cnt += word_looks_bf16(hw[i]) ? 1 : 0;
    return cnt < 16;
}

// ---- prep: swizzle W2 into MFMA B-fragment order, split hi/lo bf16 ----
// layout: wsfrag[((ks*4+nt)*64+lane)*8 + j] (hi), +4096 (lo)
template<bool ISF32>
__device__ void w2prep_body(const void* w2, short* wsfrag, int idx0) {
    #pragma unroll
    for (int i = 0; i < 2; ++i) {
        const int idx = idx0 + i * 2048;            // 0..4095
        const int j = idx & 7;
        const int lane = (idx >> 3) & 63;
        const int nt = (idx >> 9) & 3;
        const int ks = idx >> 11;
        const int src = (ks * 32 + (lane >> 4) * 8 + j) * 64 + nt * 16 + (lane & 15);
        const float v = ldin<ISF32>(w2, src);
        const short hb = bf16bits(v);
        wsfrag[idx] = hb;
        wsfrag[4096 + idx] = bf16bits(v - bf16val(hb));
    }
}

__global__ __launch_bounds__(256) void w2prep_kernel(
    const void* __restrict__ hidden, const void* __restrict__ w2,
    short* __restrict__ wsfrag) {
    const int idx0 = blockIdx.x * 256 + threadIdx.x;
    if (vote_isf32_scalar(hidden)) w2prep_body<true>(w2, wsfrag, idx0);
    else                           w2prep_body<false>(w2, wsfrag, idx0);
}

template<bool ISF32>
__device__ void qtran_body(Smem& sm,
    const void* __restrict__ hidden, const void* __restrict__ actions,
    const void* __restrict__ w1, const void* __restrict__ b1,
    const void* __restrict__ w2, const void* __restrict__ b2,
    const void* __restrict__ w3, const void* __restrict__ b3,
    void* __restrict__ out, const short* __restrict__ wsfrag, int b, int t)
{
    const int lane = t & 63;
    const int wv = t >> 6;
    const int q = lane >> 4;
    const int n = lane & 15;
    const int fq = lane & 15;
    const int rofs = lane >> 4;

    // ---- seg0: prefetch this thread's 2 W1 action rows (g=2wv+mt, a=n),
    //      k-runs f = ks*32 + q*8 + {0..7}; issue before anything else ----
    f32x4 wr[2][2][2];  // [mt][ks][half]
    #pragma unroll
    for (int mt = 0; mt < 2; ++mt) {
        const int row = ((wv * 2 + mt) * 48 + 32 + n) * 64;
        #pragma unroll
        for (int ks = 0; ks < 2; ++ks) {
            wr[mt][ks][0] = ldq<ISF32>(w1, row + ks * 32 + q * 8);
            wr[mt][ks][1] = ldq<ISF32>(w1, row + ks * 32 + q * 8 + 4);
        }
    }
    // epilogue scalars (L2-hot, issue early)
    float b2f[4], w3f[4];
    #pragma unroll
    for (int nt = 0; nt < 4; ++nt) {
        b2f[nt] = ldin<ISF32>(b2, nt * 16 + n);
        w3f[nt] = ldin<ISF32>(w3, nt * 16 + n);
    }
    const float b3f = ldin<ISF32>(b3, 0);

    // ---- seg0: stage input vector ----
    if (t < 64) {
        const int j = t >> 3, k4 = (t & 7) * 4;
        *(f32x4*)&sm.inp[j * 48 + k4] = ldq<ISF32>(hidden, (b * 8 + j) * 32 + k4);
    } else if (t < 96) {
        const int i = t - 64;
        const int j = i >> 2, c4 = (i & 3) * 4;
        *(f32x4*)&sm.inp[j * 48 + 32 + c4] = ldq<ISF32>(actions, (b * 8 + j) * 16 + c4);
    }
    __syncthreads();

    // ---- seg1: sel detect + hidden-row layer-1 partials ----
    if (t < 128) {
        const int g = t >> 4, a = t & 15;
        if (sm.inp[g * 48 + 32 + a] > 0.5f) sm.sel[g] = a;
    }
    {
        f32x4 a4 = (f32x4){0.f, 0.f, 0.f, 0.f};
        #pragma unroll 8
        for (int p = 0; p < 16; ++p) {
            const int hr = wv * 64 + p * 4 + rofs;   // hidden-row 0..255
            const int r = (hr >> 5) * 48 + (hr & 31);
            const float xv = sm.inp[r];
            const f32x4 wq = ldq<ISF32>(w1, r * 64 + fq * 4);
            #pragma unroll
            for (int c = 0; c < 4; ++c) a4[c] = fmaf(xv, wq[c], a4[c]);
        }
        #pragma unroll
        for (int c = 0; c < 4; ++c) {
            a4[c] += __shfl_xor(a4[c], 16);
            a4[c] += __shfl_xor(a4[c], 32);
        }
        if (rofs == 0) *(f32x4*)&sm.part[wv][fq * 4] = a4;
    }
    __syncthreads();

    // ---- seg2: sub rows / base / subsum, disjoint thread groups ----
    if (t < 128) {
        const int g = t >> 4, f4 = (t & 15) * 4;
        *(f32x4*)&sm.sub[g][f4] =
            ldq<ISF32>(w1, (g * 48 + 32 + sm.sel[g]) * 64 + f4);
    } else if (t < 192) {
        const int f = t - 128;
        sm.base[f] = ldin<ISF32>(b1, f) + sm.part[0][f] + sm.part[1][f]
                   + sm.part[2][f] + sm.part[3][f];
    } else {
        const int f = t - 192;
        float s = 0.f;
        #pragma unroll
        for (int g = 0; g < 8; ++g)
            s += ldin<ISF32>(w1, (g * 48 + 32 + sm.sel[g]) * 64 + f);
        sm.subsum[f] = s;
    }
    __syncthreads();

    // ---- seg3: build A-fragments in registers ----
    // thread covers items {wv*32+n, wv*32+16+n} (agents 2wv, 2wv+1, action n),
    // k = ks*32 + q*8 + j  ->  f-runs q*8..q*8+7 per ks
    f32x4 bsA[2][2];     // baseAll = base + subsum, per [ks][half]
    #pragma unroll
    for (int ks = 0; ks < 2; ++ks)
      #pragma unroll
      for (int h = 0; h < 2; ++h) {
        const int f0 = ks * 32 + q * 8 + h * 4;
        const f32x4 bb = *(const f32x4*)&sm.base[f0];
        const f32x4 ss = *(const f32x4*)&sm.subsum[f0];
        bsA[ks][h] = (f32x4){bb[0] + ss[0], bb[1] + ss[1], bb[2] + ss[2], bb[3] + ss[3]};
      }
    bf16x8 ahi[2][2];    // [ks][mt]
    #pragma unroll
    for (int mt = 0; mt < 2; ++mt) {
        const int g = wv * 2 + mt;
        #pragma unroll
        for (int ks = 0; ks < 2; ++ks) {
            #pragma unroll
            for (int h = 0; h < 2; ++h) {
                const int f0 = ks * 32 + q * 8 + h * 4;
                const f32x4 sg = *(const f32x4*)&sm.sub[g][f0];
                const f32x4 w4 = wr[mt][ks][h];
                #pragma unroll
                for (int c = 0; c < 4; ++c) {
                    const float v = fmaxf(bsA[ks][h][c] - sg[c] + w4[c], 0.f);
                    ahi[ks][mt][h * 4 + c] = bf16bits(v);
                }
            }
        }
    }

    // ---- seg4: layer 2, split-W2 mfma_f32_16x16x32_bf16 ----
    f32x4 acc[2][4];
    #pragma unroll
    for (int mt = 0; mt < 2; ++mt)
      #pragma unroll
      for (int nt = 0; nt < 4; ++nt)
        acc[mt][nt] = (f32x4){0.f, 0.f, 0.f, 0.f};

    #pragma unroll
    for (int ks = 0; ks < 2; ++ks) {
        #pragma unroll
        for (int nt = 0; nt < 4; ++nt) {
            bf16x8 bhi, blo;
            if (wsfrag) {
                const int fb = ((ks * 4 + nt) * 64 + lane) * 8;
                bhi = *(const bf16x8*)&wsfrag[fb];
                blo = *(const bf16x8*)&wsfrag[4096 + fb];
            } else {
                #pragma unroll
                for (int j = 0; j < 8; ++j) {
                    const float v = ldin<ISF32>(w2, (ks * 32 + q * 8 + j) * 64 + nt * 16 + n);
                    const short hb = bf16bits(v);
                    bhi[j] = hb;
                    blo[j] = bf16bits(v - bf16val(hb));
                }
            }
            #pragma unroll
            for (int mt = 0; mt < 2; ++mt) {
                acc[mt][nt] = __builtin_amdgcn_mfma_f32_16x16x32_bf16(
                    ahi[ks][mt], bhi, acc[mt][nt], 0, 0, 0);
                acc[mt][nt] = __builtin_amdgcn_mfma_f32_16x16x32_bf16(
                    ahi[ks][mt], blo, acc[mt][nt], 0, 0, 0);
            }
        }
    }

    // ---- epilogue: h2 = relu(acc + b2); qv = h2 . w3 + b3 ----
    #pragma unroll
    for (int mt = 0; mt < 2; ++mt) {
      #pragma unroll
      for (int r = 0; r < 4; ++r) {
        float p = 0.f;
        #pragma unroll
        for (int nt = 0; nt < 4; ++nt) {
            const float h2 = fmaxf(acc[mt][nt][r] + b2f[nt], 0.f);  // D: row=q*4+r, col=n
            p = fmaf(h2, w3f[nt], p);
        }
        p += __shfl_xor(p, 1);
        p += __shfl_xor(p, 2);
        p += __shfl_xor(p, 4);
        p += __shfl_xor(p, 8);
        if (n == mt * 4 + r) {
            const int item = wv * 32 + mt * 16 + q * 4 + r;
            if constexpr (ISF32) ((float*)out)[b * 128 + item] = p + b3f;
            else ((__hip_bfloat16*)out)[b * 128 + item] = __float2bfloat16(p + b3f);
        }
      }
    }
}

__global__ __launch_bounds__(256, 4) void qtran_cf_kernel(
    const void* __restrict__ hidden, const void* __restrict__ actions,
    const void* __restrict__ w1, const void* __restrict__ b1,
    const void* __restrict__ w2, const void* __restrict__ b2,
    const void* __restrict__ w3, const void* __restrict__ b3,
    void* __restrict__ out, const short* __restrict__ wsfrag)
{
    __shared__ Smem sm;
    // dtype vote, lane-parallel
    const unsigned int* hw = (const unsigned int*)hidden;
    const bool pass = word_looks_bf16(hw[threadIdx.x & 31]);
    const unsigned long long m = __ballot(pass);
    const bool isf32 = (__popcll(m) < 32);

    const int b = blockIdx.x;
    const int t = threadIdx.x;
    if (isf32)
        qtran_body<true>(sm, hidden, actions, w1, b1, w2, b2, w3, b3, out, wsfrag, b, t);
    else
        qtran_body<false>(sm, hidden, actions, w1, b1, w2, b2, w3, b3, out, wsfrag, b, t);
}

extern "C" void kernel_launch(void* const* d_in, const int* in_sizes, int n_in,
                              void* d_out, int out_size, void* d_ws, size_t ws_size,
                              hipStream_t stream) {
    short* wsfrag = (ws_size >= 16384) ? (short*)d_ws : nullptr;
    if (wsfrag)
        w2prep_kernel<<<8, 256, 0, stream>>>(d_in[0], d_in[4], wsfrag);
    qtran_cf_kernel<<<2048, 256, 0, stream>>>(
        d_in[0], d_in[1], d_in[2], d_in[3], d_in[4], d_in[5], d_in[6], d_in[7],
        d_out, wsfrag);
}

// Round 8
// 87.972 us; speedup vs baseline: 1.0260x; 1.0260x over previous
//
#include <hip/hip_runtime.h>
#include <hip/hip_bf16.h>

typedef __attribute__((ext_vector_type(4))) float f32x4;
typedef __attribute__((ext_vector_type(8))) short bf16x8;

#define NB 4       // batch items per block
#define W1A_S 68   // padded f32 stride for staged W1 action rows

struct Smem {
    float inp[NB][384];                  // per-item input vectors (real actions)
    float part[4][NB][64];               // layer-1 hidden partials per wave
    float baseAll[NB][64];               // b1 + hidden part + sum_g sub  (= base1)
    float sub[NB][8][64];                // W1 action row of agent g's real action
    __align__(16) float w1act[128 * W1A_S]; // all 128 W1 action rows, staged
    int sel[NB][8];
};

template<bool ISF32>
__device__ __forceinline__ float ldin(const void* p, int i) {
    if constexpr (ISF32) return ((const float*)p)[i];
    else return __bfloat162float(((const __hip_bfloat16*)p)[i]);
}

template<bool ISF32>
__device__ __forceinline__ f32x4 ldq(const void* p, int i) {
    if constexpr (ISF32) return *(const f32x4*)((const float*)p + i);
    else {
        const __hip_bfloat16* q = (const __hip_bfloat16*)p + i;
        return (f32x4){__bfloat162float(q[0]), __bfloat162float(q[1]),
                       __bfloat162float(q[2]), __bfloat162float(q[3])};
    }
}

__device__ __forceinline__ short bf16bits(float v) {
    __hip_bfloat16 h = __float2bfloat16(v);
    return *(const short*)&h;
}
__device__ __forceinline__ float bf16val(short s) {
    return __bfloat162float(*(const __hip_bfloat16*)&s);
}

__device__ __forceinline__ bool word_looks_bf16(unsigned int w) {
    const unsigned int lo = w & 0xFFFFu;
    const unsigned int ex = (lo >> 7) & 0xFFu;
    return (ex >= 100u && ex <= 140u) || (lo & 0x7FFFu) == 0u;
}

__device__ __forceinline__ bool vote_isf32_scalar(const void* hidden) {
    const unsigned int* hw = (const unsigned int*)hidden;
    int cnt = 0;
    #pragma unroll
    for (int i = 0; i < 32; ++i) cnt += word_looks_bf16(hw[i]) ? 1 : 0;
    return cnt < 16;
}

// ---- prep: swizzle W2 into MFMA B-fragment order, split hi/lo bf16 ----
// layout: wsfrag[((ks*4+nt)*64+lane)*8 + j] (hi), +4096 (lo)
template<bool ISF32>
__device__ void w2prep_body(const void* w2, short* wsfrag, int idx0) {
    #pragma unroll
    for (int i = 0; i < 2; ++i) {
        const int idx = idx0 + i * 2048;            // 0..4095
        const int j = idx & 7;
        const int lane = (idx >> 3) & 63;
        const int nt = (idx >> 9) & 3;
        const int ks = idx >> 11;
        const int src = (ks * 32 + (lane >> 4) * 8 + j) * 64 + nt * 16 + (lane & 15);
        const float v = ldin<ISF32>(w2, src);
        const short hb = bf16bits(v);
        wsfrag[idx] = hb;
        wsfrag[4096 + idx] = bf16bits(v - bf16val(hb));
    }
}

__global__ __launch_bounds__(256) void w2prep_kernel(
    const void* __restrict__ hidden, const void* __restrict__ w2,
    short* __restrict__ wsfrag) {
    const int idx0 = blockIdx.x * 256 + threadIdx.x;
    if (vote_isf32_scalar(hidden)) w2prep_body<true>(w2, wsfrag, idx0);
    else                           w2prep_body<false>(w2, wsfrag, idx0);
}

template<bool ISF32>
__device__ void qtran_body(Smem& sm,
    const void* __restrict__ hidden, const void* __restrict__ actions,
    const void* __restrict__ w1, const void* __restrict__ b1,
    const void* __restrict__ w2, const void* __restrict__ b2,
    const void* __restrict__ w3, const void* __restrict__ b3,
    void* __restrict__ out, const short* __restrict__ wsfrag, int blk, int t)
{
    const int lane = t & 63;
    const int wv = t >> 6;
    const int q = lane >> 4;
    const int n = lane & 15;
    const int fq = n;          // f-quad for layer-1
    const int rofs = q;        // row-offset group for layer-1
    const int b0 = blk * NB;

    // ---- B-fragments for layer-2 (global, issue early; held in regs) ----
    bf16x8 bhi[2][4], blo[2][4];
    if (wsfrag) {
        #pragma unroll
        for (int ks = 0; ks < 2; ++ks)
          #pragma unroll
          for (int nt = 0; nt < 4; ++nt) {
            const int fb = ((ks * 4 + nt) * 64 + lane) * 8;
            bhi[ks][nt] = *(const bf16x8*)&wsfrag[fb];
            blo[ks][nt] = *(const bf16x8*)&wsfrag[4096 + fb];
          }
    } else {
        #pragma unroll
        for (int ks = 0; ks < 2; ++ks)
          #pragma unroll
          for (int nt = 0; nt < 4; ++nt)
            #pragma unroll
            for (int j = 0; j < 8; ++j) {
                const float v = ldin<ISF32>(w2, (ks * 32 + q * 8 + j) * 64 + nt * 16 + n);
                const short hb = bf16bits(v);
                bhi[ks][nt][j] = hb;
                blo[ks][nt][j] = bf16bits(v - bf16val(hb));
            }
    }

    // ---- seg0: stage inputs (4 items) + all 128 W1 action rows ----
    {
        const int i0 = t >> 6, s = t & 63;
        const int j = s >> 3, k4 = (s & 7) * 4;
        *(f32x4*)&sm.inp[i0][j * 48 + k4] =
            ldq<ISF32>(hidden, ((b0 + i0) * 8 + j) * 32 + k4);
        if (s < 32) {
            const int ja = s >> 2, c4 = (s & 3) * 4;
            *(f32x4*)&sm.inp[i0][ja * 48 + 32 + c4] =
                ldq<ISF32>(actions, ((b0 + i0) * 8 + ja) * 16 + c4);
        }
    }
    #pragma unroll
    for (int p = 0; p < 8; ++p) {
        const int idx = p * 256 + t;
        const int row = idx >> 4, qd = idx & 15;
        *(f32x4*)&sm.w1act[row * W1A_S + qd * 4] =
            ldq<ISF32>(w1, ((row >> 4) * 48 + 32 + (row & 15)) * 64 + qd * 4);
    }
    __syncthreads();

    // ---- seg1: sel detect + layer-1 hidden partials (16 FMA per W1 ldq) ----
    {
        const int i0 = t >> 6, s = t & 63, a = s & 15;
        const int g1 = s >> 4;
        if (sm.inp[i0][g1 * 48 + 32 + a] > 0.5f) sm.sel[i0][g1] = a;
        const int g2 = g1 + 4;
        if (sm.inp[i0][g2 * 48 + 32 + a] > 0.5f) sm.sel[i0][g2] = a;
    }
    {
        f32x4 a4[NB];
        #pragma unroll
        for (int i = 0; i < NB; ++i) a4[i] = (f32x4){0.f, 0.f, 0.f, 0.f};
        #pragma unroll 8
        for (int p = 0; p < 16; ++p) {
            const int hr = wv * 64 + p * 4 + rofs;       // hidden-row 0..255
            const int r = (hr >> 5) * 48 + (hr & 31);
            const f32x4 wq = ldq<ISF32>(w1, r * 64 + fq * 4);
            #pragma unroll
            for (int i = 0; i < NB; ++i) {
                const float xv = sm.inp[i][r];           // LDS broadcast
                #pragma unroll
                for (int c = 0; c < 4; ++c) a4[i][c] = fmaf(xv, wq[c], a4[i][c]);
            }
        }
        #pragma unroll
        for (int i = 0; i < NB; ++i)
          #pragma unroll
          for (int c = 0; c < 4; ++c) {
            a4[i][c] += __shfl_xor(a4[i][c], 16);
            a4[i][c] += __shfl_xor(a4[i][c], 32);
          }
        if (rofs == 0) {
            #pragma unroll
            for (int i = 0; i < NB; ++i)
                *(f32x4*)&sm.part[wv][i][fq * 4] = a4[i];
        }
    }
    __syncthreads();

    // ---- seg2a: sub rows = staged W1 action row of selected action ----
    #pragma unroll
    for (int p = 0; p < 2; ++p) {
        const int idx = p * 256 + t;                     // 0..511
        const int i = idx >> 7, g = (idx >> 4) & 7, qd = idx & 15;
        const int row = g * 16 + sm.sel[i][g];
        *(f32x4*)&sm.sub[i][g][qd * 4] =
            *(const f32x4*)&sm.w1act[row * W1A_S + qd * 4];
    }
    __syncthreads();

    // ---- seg2b: baseAll = b1 + hidden partials + sum_g sub  (= base1) ----
    {
        const int i = t >> 6, f = t & 63;
        float v = ldin<ISF32>(b1, f);
        #pragma unroll
        for (int w = 0; w < 4; ++w) v += sm.part[w][i][f];
        #pragma unroll
        for (int g = 0; g < 8; ++g) v += sm.sub[i][g][f];
        sm.baseAll[i][f] = v;
    }
    __syncthreads();

    // ---- seg3: wave wv owns batch item (b0+wv); loop agents g=0..7 ----
    f32x4 bA[2][2];
    #pragma unroll
    for (int ks = 0; ks < 2; ++ks)
      #pragma unroll
      for (int h = 0; h < 2; ++h)
        bA[ks][h] = *(const f32x4*)&sm.baseAll[wv][ks * 32 + q * 8 + h * 4];

    float b2f[4], w3f[4];
    #pragma unroll
    for (int nt = 0; nt < 4; ++nt) {
        b2f[nt] = ldin<ISF32>(b2, nt * 16 + n);
        w3f[nt] = ldin<ISF32>(w3, nt * 16 + n);
    }
    const float b3f = ldin<ISF32>(b3, 0);

    for (int g = 0; g < 8; ++g) {
        // A-fragment: cf-item (g, a=n), k = ks*32 + q*8 + j
        bf16x8 af[2];
        const int arow = (g * 16 + n) * W1A_S;
        #pragma unroll
        for (int ks = 0; ks < 2; ++ks)
          #pragma unroll
          for (int h = 0; h < 2; ++h) {
            const int f0 = ks * 32 + q * 8 + h * 4;
            const f32x4 sg = *(const f32x4*)&sm.sub[wv][g][f0];   // broadcast
            const f32x4 wA = *(const f32x4*)&sm.w1act[arow + f0];
            #pragma unroll
            for (int c = 0; c < 4; ++c) {
                const float v = fmaxf(bA[ks][h][c] - sg[c] + wA[c], 0.f);
                af[ks][h * 4 + c] = bf16bits(v);
            }
          }

        f32x4 acc[4];
        #pragma unroll
        for (int nt = 0; nt < 4; ++nt) acc[nt] = (f32x4){0.f, 0.f, 0.f, 0.f};
        #pragma unroll
        for (int ks = 0; ks < 2; ++ks)
          #pragma unroll
          for (int nt = 0; nt < 4; ++nt) {
            acc[nt] = __builtin_amdgcn_mfma_f32_16x16x32_bf16(
                af[ks], bhi[ks][nt], acc[nt], 0, 0, 0);
            acc[nt] = __builtin_amdgcn_mfma_f32_16x16x32_bf16(
                af[ks], blo[ks][nt], acc[nt], 0, 0, 0);
          }

        // epilogue: h2 = relu(acc + b2); qv = h2 . w3 + b3
        #pragma unroll
        for (int r = 0; r < 4; ++r) {
            float p = 0.f;
            #pragma unroll
            for (int nt = 0; nt < 4; ++nt) {
                const float h2 = fmaxf(acc[nt][r] + b2f[nt], 0.f); // D: row=q*4+r, col=n
                p = fmaf(h2, w3f[nt], p);
            }
            p += __shfl_xor(p, 1);
            p += __shfl_xor(p, 2);
            p += __shfl_xor(p, 4);
            p += __shfl_xor(p, 8);
            if (n == r) {
                const int oi = (b0 + wv) * 128 + g * 16 + q * 4 + r;
                if constexpr (ISF32) ((float*)out)[oi] = p + b3f;
                else ((__hip_bfloat16*)out)[oi] = __float2bfloat16(p + b3f);
            }
        }
    }
}

__global__ __launch_bounds__(256, 2) void qtran_cf_kernel(
    const void* __restrict__ hidden, const void* __restrict__ actions,
    const void* __restrict__ w1, const void* __restrict__ b1,
    const void* __restrict__ w2, const void* __restrict__ b2,
    const void* __restrict__ w3, const void* __restrict__ b3,
    void* __restrict__ out, const short* __restrict__ wsfrag)
{
    __shared__ Smem sm;
    // dtype vote, lane-parallel
    const unsigned int* hw = (const unsigned int*)hidden;
    const bool pass = word_looks_bf16(hw[threadIdx.x & 31]);
    const unsigned long long m = __ballot(pass);
    const bool isf32 = (__popcll(m) < 32);

    const int blk = blockIdx.x;
    const int t = threadIdx.x;
    if (isf32)
        qtran_body<true>(sm, hidden, actions, w1, b1, w2, b2, w3, b3, out, wsfrag, blk, t);
    else
        qtran_body<false>(sm, hidden, actions, w1, b1, w2, b2, w3, b3, out, wsfrag, blk, t);
}

extern "C" void kernel_launch(void* const* d_in, const int* in_sizes, int n_in,
                              void* d_out, int out_size, void* d_ws, size_t ws_size,
                              hipStream_t stream) {
    short* wsfrag = (ws_size >= 16384) ? (short*)d_ws : nullptr;
    if (wsfrag)
        w2prep_kernel<<<8, 256, 0, stream>>>(d_in[0], d_in[4], wsfrag);
    qtran_cf_kernel<<<512, 256, 0, stream>>>(
        d_in[0], d_in[1], d_in[2], d_in[3], d_in[4], d_in[5], d_in[6], d_in[7],
        d_out, wsfrag);
}

// Round 9
// 85.507 us; speedup vs baseline: 1.0555x; 1.0288x over previous
//
#include <hip/hip_runtime.h>
#include <hip/hip_bf16.h>

typedef __attribute__((ext_vector_type(4))) float f32x4;
typedef __attribute__((ext_vector_type(8))) short bf16x8;
typedef __attribute__((ext_vector_type(4))) short s16x4;

#define H1S 72  // padded bf16 stride (144 B rows: 16B-aligned)

struct Smem {
    float inp[384];          // base input vector (real actions), f32
    float base[64];          // b1 + hidden-part of layer 1 (no action rows)
    float sub[8][64];        // sub[g][f] = W1 row of agent g's real action
    int   sel[8];            // real-action index per agent
    union {                  // part's last read is barrier-separated from h1's first write
        float part[4][64];
        __align__(16) short h1[128 * H1S];  // h1 in bf16
    } u;
};

template<bool ISF32>
__device__ __forceinline__ float ldin(const void* p, int i) {
    if constexpr (ISF32) return ((const float*)p)[i];
    else return __bfloat162float(((const __hip_bfloat16*)p)[i]);
}

template<bool ISF32>
__device__ __forceinline__ f32x4 ldq(const void* p, int i) {
    if constexpr (ISF32) return *(const f32x4*)((const float*)p + i);
    else {
        const __hip_bfloat16* q = (const __hip_bfloat16*)p + i;
        return (f32x4){__bfloat162float(q[0]), __bfloat162float(q[1]),
                       __bfloat162float(q[2]), __bfloat162float(q[3])};
    }
}

__device__ __forceinline__ short bf16bits(float v) {
    __hip_bfloat16 h = __float2bfloat16(v);
    return *(const short*)&h;
}
__device__ __forceinline__ float bf16val(short s) {
    return __bfloat162float(*(const __hip_bfloat16*)&s);
}

__device__ __forceinline__ bool word_looks_bf16(unsigned int w) {
    const unsigned int lo = w & 0xFFFFu;
    const unsigned int ex = (lo >> 7) & 0xFFu;
    return (ex >= 100u && ex <= 140u) || (lo & 0x7FFFu) == 0u;
}

__device__ __forceinline__ bool vote_isf32_scalar(const void* hidden) {
    const unsigned int* hw = (const unsigned int*)hidden;
    int cnt = 0;
    #pragma unroll
    for (int i = 0; i < 32; ++i) cnt += word_looks_bf16(hw[i]) ? 1 : 0;
    return cnt < 16;
}

// ---- prep: swizzle W2 into MFMA B-fragment order, split hi/lo bf16 ----
// layout: wsfrag[((ks*4+nt)*64+lane)*8 + j] (hi), +4096 (lo)
template<bool ISF32>
__device__ void w2prep_body(const void* w2, short* wsfrag, int idx0) {
    #pragma unroll
    for (int i = 0; i < 2; ++i) {
        const int idx = idx0 + i * 2048;            // 0..4095
        const int j = idx & 7;
        const int lane = (idx >> 3) & 63;
        const int nt = (idx >> 9) & 3;
        const int ks = idx >> 11;
        const int src = (ks * 32 + (lane >> 4) * 8 + j) * 64 + nt * 16 + (lane & 15);
        const float v = ldin<ISF32>(w2, src);
        const short hb = bf16bits(v);
        wsfrag[idx] = hb;
        wsfrag[4096 + idx] = bf16bits(v - bf16val(hb));
    }
}

__global__ __launch_bounds__(256) void w2prep_kernel(
    const void* __restrict__ hidden, const void* __restrict__ w2,
    short* __restrict__ wsfrag) {
    const int idx0 = blockIdx.x * 256 + threadIdx.x;
    if (vote_isf32_scalar(hidden)) w2prep_body<true>(w2, wsfrag, idx0);
    else                           w2prep_body<false>(w2, wsfrag, idx0);
}

// W2D: true -> build B-fragments directly from w2 (no workspace)
template<bool ISF32, bool W2D>
__device__ void qtran_body(Smem& sm,
    const void* __restrict__ hidden, const void* __restrict__ actions,
    const void* __restrict__ w1, const void* __restrict__ b1,
    const void* __restrict__ w2, const void* __restrict__ b2,
    const void* __restrict__ w3, const void* __restrict__ b3,
    void* __restrict__ out, const short* __restrict__ wsfrag, int b, int t)
{
    const int lane = t & 63;
    const int wv = t >> 6;
    const int q = lane >> 4;
    const int n = lane & 15;
    const int fq = lane & 15;
    const int rofs = lane >> 4;

    // ---- phase 0: stage input vector (f32x4 loads) ----
    if (t < 64) {
        const int j = t >> 3, k4 = (t & 7) * 4;
        *(f32x4*)&sm.inp[j * 48 + k4] = ldq<ISF32>(hidden, (b * 8 + j) * 32 + k4);
    } else if (t < 96) {
        const int i = t - 64;
        const int j = i >> 2, c4 = (i & 3) * 4;
        *(f32x4*)&sm.inp[j * 48 + 32 + c4] = ldq<ISF32>(actions, (b * 8 + j) * 16 + c4);
    }
    __syncthreads();

    // ---- phase 1a: find each agent's real-action index (one-hot) ----
    if (t < 128) {
        const int g = t >> 4, a = t & 15;
        if (sm.inp[g * 48 + 32 + a] > 0.5f) sm.sel[g] = a;
    }

    // ---- phase 1: hidden-row layer-1 partials; wave wv covers 64 of 256 rows ----
    {
        f32x4 a4 = (f32x4){0.f, 0.f, 0.f, 0.f};
        #pragma unroll 8
        for (int p = 0; p < 16; ++p) {
            const int hr = wv * 64 + p * 4 + rofs;   // hidden-row 0..255
            const int r = (hr >> 5) * 48 + (hr & 31);
            const float xv = sm.inp[r];
            const f32x4 wq = ldq<ISF32>(w1, r * 64 + fq * 4);
            #pragma unroll
            for (int c = 0; c < 4; ++c) a4[c] = fmaf(xv, wq[c], a4[c]);
        }
        #pragma unroll
        for (int c = 0; c < 4; ++c) {
            a4[c] += __shfl_xor(a4[c], 16);
            a4[c] += __shfl_xor(a4[c], 32);
        }
        if (rofs == 0) *(f32x4*)&sm.u.part[wv][fq * 4] = a4;
    }
    __syncthreads();

    // ---- phase 2: sub rows / base, disjoint thread groups ----
    if (t < 128) {
        const int g = t >> 4, f4 = (t & 15) * 4;
        *(f32x4*)&sm.sub[g][f4] =
            ldq<ISF32>(w1, (g * 48 + 32 + sm.sel[g]) * 64 + f4);
    } else if (t < 192) {
        const int f = t - 128;
        sm.base[f] = ldin<ISF32>(b1, f) + sm.u.part[0][f] + sm.u.part[1][f]
                   + sm.u.part[2][f] + sm.u.part[3][f];
    }
    __syncthreads();

    // ---- phase 4: h1 for 128 items -> bf16 LDS ----
    {
        const int itm = t >> 4;                      // 16 items per pass
        const int hfq = t & 15;
        f32x4 S = *(const f32x4*)&sm.sub[0][hfq * 4];
        #pragma unroll
        for (int g = 1; g < 8; ++g) {
            const f32x4 sg = *(const f32x4*)&sm.sub[g][hfq * 4];
            #pragma unroll
            for (int c = 0; c < 4; ++c) S[c] += sg[c];
        }
        f32x4 bs = *(const f32x4*)&sm.base[hfq * 4];
        #pragma unroll
        for (int c = 0; c < 4; ++c) bs[c] += S[c];   // base incl. all real actions
        #pragma unroll
        for (int p = 0; p < 8; ++p) {
            const int item = p * 16 + itm;
            const int g = item >> 4, a = item & 15;
            const f32x4 wq = ldq<ISF32>(w1, (g * 48 + 32 + a) * 64 + hfq * 4);
            const f32x4 sb = *(const f32x4*)&sm.sub[g][hfq * 4];
            s16x4 hi;
            #pragma unroll
            for (int c = 0; c < 4; ++c)
                hi[c] = bf16bits(fmaxf(bs[c] - sb[c] + wq[c], 0.f));
            *(s16x4*)&sm.u.h1[item * H1S + hfq * 4] = hi;
        }
    }
    __syncthreads();

    // ---- phase 5: layer 2; B-frags loaded per-ks HERE (low VGPR peak) ----
    f32x4 acc[2][4];
    #pragma unroll
    for (int mt = 0; mt < 2; ++mt)
      #pragma unroll
      for (int nt = 0; nt < 4; ++nt)
        acc[mt][nt] = (f32x4){0.f, 0.f, 0.f, 0.f};

    #pragma unroll
    for (int ks = 0; ks < 2; ++ks) {
        bf16x8 ahi[2];
        #pragma unroll
        for (int mt = 0; mt < 2; ++mt) {
            const int item = wv * 32 + mt * 16 + n;  // A[m=lane&15][k=quad*8+j]
            ahi[mt] = *(const bf16x8*)&sm.u.h1[item * H1S + ks * 32 + q * 8];
        }
        bf16x8 bhi[4], blo[4];
        if constexpr (!W2D) {
            #pragma unroll
            for (int nt = 0; nt < 4; ++nt) {
                const int fb = ((ks * 4 + nt) * 64 + lane) * 8;
                bhi[nt] = *(const bf16x8*)&wsfrag[fb];
                blo[nt] = *(const bf16x8*)&wsfrag[4096 + fb];
            }
        } else {
            #pragma unroll
            for (int nt = 0; nt < 4; ++nt)
                #pragma unroll
                for (int j = 0; j < 8; ++j) {
                    const float v = ldin<ISF32>(w2, (ks * 32 + q * 8 + j) * 64 + nt * 16 + n);
                    const short hb = bf16bits(v);
                    bhi[nt][j] = hb;
                    blo[nt][j] = bf16bits(v - bf16val(hb));
                }
        }
        #pragma unroll
        for (int nt = 0; nt < 4; ++nt)
            #pragma unroll
            for (int mt = 0; mt < 2; ++mt) {
                acc[mt][nt] = __builtin_amdgcn_mfma_f32_16x16x32_bf16(
                    ahi[mt], bhi[nt], acc[mt][nt], 0, 0, 0);
                acc[mt][nt] = __builtin_amdgcn_mfma_f32_16x16x32_bf16(
                    ahi[mt], blo[nt], acc[mt][nt], 0, 0, 0);
            }
    }

    // ---- epilogue: h2 = relu(acc + b2); qv = h2 . w3 + b3 ----
    float b2f[4], w3f[4];
    #pragma unroll
    for (int nt = 0; nt < 4; ++nt) {
        b2f[nt] = ldin<ISF32>(b2, nt * 16 + n);
        w3f[nt] = ldin<ISF32>(w3, nt * 16 + n);
    }
    const float b3f = ldin<ISF32>(b3, 0);

    #pragma unroll
    for (int mt = 0; mt < 2; ++mt) {
      #pragma unroll
      for (int r = 0; r < 4; ++r) {
        float p = 0.f;
        #pragma unroll
        for (int nt = 0; nt < 4; ++nt) {
            const float h2 = fmaxf(acc[mt][nt][r] + b2f[nt], 0.f); // D: row=q*4+r, col=n
            p = fmaf(h2, w3f[nt], p);
        }
        p += __shfl_xor(p, 1);
        p += __shfl_xor(p, 2);
        p += __shfl_xor(p, 4);
        p += __shfl_xor(p, 8);
        if (n == mt * 4 + r) {
            const int item = wv * 32 + mt * 16 + q * 4 + r;
            if constexpr (ISF32) ((float*)out)[b * 128 + item] = p + b3f;
            else ((__hip_bfloat16*)out)[b * 128 + item] = __float2bfloat16(p + b3f);
        }
      }
    }
}

template<bool W2D>
__global__ __launch_bounds__(256, 4) void qtran_cf_kernel(
    const void* __restrict__ hidden, const void* __restrict__ actions,
    const void* __restrict__ w1, const void* __restrict__ b1,
    const void* __restrict__ w2, const void* __restrict__ b2,
    const void* __restrict__ w3, const void* __restrict__ b3,
    void* __restrict__ out, const short* __restrict__ wsfrag)
{
    __shared__ Smem sm;
    // dtype vote, lane-parallel
    const unsigned int* hw = (const unsigned int*)hidden;
    const bool pass = word_looks_bf16(hw[threadIdx.x & 31]);
    const unsigned long long m = __ballot(pass);
    const bool isf32 = (__popcll(m) < 32);

    const int b = blockIdx.x;
    const int t = threadIdx.x;
    if (isf32)
        qtran_body<true, W2D>(sm, hidden, actions, w1, b1, w2, b2, w3, b3, out, wsfrag, b, t);
    else
        qtran_body<false, W2D>(sm, hidden, actions, w1, b1, w2, b2, w3, b3, out, wsfrag, b, t);
}

extern "C" void kernel_launch(void* const* d_in, const int* in_sizes, int n_in,
                              void* d_out, int out_size, void* d_ws, size_t ws_size,
                              hipStream_t stream) {
    short* wsfrag = (ws_size >= 16384) ? (short*)d_ws : nullptr;
    if (wsfrag) {
        w2prep_kernel<<<8, 256, 0, stream>>>(d_in[0], d_in[4], wsfrag);
        qtran_cf_kernel<false><<<2048, 256, 0, stream>>>(
            d_in[0], d_in[1], d_in[2], d_in[3], d_in[4], d_in[5], d_in[6], d_in[7],
            d_out, wsfrag);
    } else {
        qtran_cf_kernel<true><<<2048, 256, 0, stream>>>(
            d_in[0], d_in[1], d_in[2], d_in[3], d_in[4], d_in[5], d_in[6], d_in[7],
            d_out, nullptr);
    }
}